// Round 2
// baseline (78.129 us; speedup 1.0000x reference)
//
#include <hip/hip_runtime.h>

#define N_ROWS 8192
#define K_CENT 128
#define D_DIM  512
#define LDS_PITCH 520   // 512 + 8 pad ushorts; row stride 1040B (16B-aligned), dword
                        // stride 260 == 4 (mod 32) -> ds_read_b128 hits the bank floor

typedef short v8s __attribute__((ext_vector_type(8)));
typedef float v4f __attribute__((ext_vector_type(4)));

union U16B { v8s v; unsigned u[4]; };

// HW packed fp32->bf16 (RNE via MODE default): dst = [bf16(lo) | bf16(hi)<<16]
__device__ inline unsigned cvt2bf(float lo, float hi) {
    unsigned r;
    asm("v_cvt_pk_bf16_f32 %0, %1, %2" : "=v"(r) : "v"(lo), "v"(hi));
    return r;
}

// Single fused kernel, latency-optimized: 512 blocks x 512 threads (8 waves),
// 16 rows per block, ONE LDS tile, ONE barrier. __launch_bounds__(512,4) ->
// 2 blocks/CU resident (4 waves/SIMD): while block A sits in its barrier or a
// load-latency window, block B issues -- the serial per-block chain
// {x-loads -> c-prologue -> stage -> barrier -> MFMA} is half the length of
// the previous 32-row double-buffered version and overlaps across blocks.
// Wave g converts its 16 centroids fp32->bf16 once into registers (bfr[16])
// and accumulates exact fp32 ||c||^2 from the same loads; ||x||^2 is exact
// fp32 folded into staging (butterfly -> xn[]).
__global__ __launch_bounds__(512, 4) void dist_fused(const float* __restrict__ x,
                                                     const float* __restrict__ c,
                                                     float* __restrict__ out) {
    __shared__ unsigned short xlds[16 * LDS_PITCH];
    __shared__ __align__(16) float xn[16];

    const int t    = threadIdx.x;
    const int lane = t & 63;
    const int g    = t >> 6;             // wave index == centroid group 0..7
    const int n16  = lane & 15;
    const int quad = lane >> 4;
    const int rowbase = blockIdx.x * 16;

    // ---- issue x-tile loads first (latency overlaps centroid prologue) ----
    // thread t covers floats {t*8 .. t*8+7} of row g and row 8+g (col lane*8)
    const float* xs = x + (size_t)rowbase * D_DIM;
    float4 a00 = *(const float4*)(xs + t * 8);
    float4 a01 = *(const float4*)(xs + t * 8 + 4);
    float4 a10 = *(const float4*)(xs + 4096 + t * 8);
    float4 a11 = *(const float4*)(xs + 4096 + t * 8 + 4);

    // ---- centroid prologue: group g, row n16, quad's k-slices ----
    const float* cp = c + (size_t)(g * 16 + n16) * D_DIM + quad * 8;
    v8s bfr[16];
    float cn0 = 0.f, cn1 = 0.f, cn2 = 0.f, cn3 = 0.f;
#pragma unroll
    for (int i = 0; i < 16; ++i) {
        float4 u0 = *(const float4*)(cp + i * 32);
        float4 u1 = *(const float4*)(cp + i * 32 + 4);
        U16B b;
        b.u[0] = cvt2bf(u0.x, u0.y); b.u[1] = cvt2bf(u0.z, u0.w);
        b.u[2] = cvt2bf(u1.x, u1.y); b.u[3] = cvt2bf(u1.z, u1.w);
        bfr[i] = b.v;
        cn0 += u0.x * u0.x + u0.y * u0.y;
        cn1 += u0.z * u0.z + u0.w * u0.w;
        cn2 += u1.x * u1.x + u1.y * u1.y;
        cn3 += u1.z * u1.z + u1.w * u1.w;
    }
    float cn = (cn0 + cn1) + (cn2 + cn3);
    cn += __shfl_xor(cn, 16, 64);        // reduce across quad bits (lane bits 4,5)
    cn += __shfl_xor(cn, 32, 64);        // -> exact fp32 ||c[g*16+n16]||^2

    // ---- stage x tile -> LDS (bf16) + exact fp32 row norms ----
    {
        U16B p0, p1;
        p0.u[0] = cvt2bf(a00.x, a00.y); p0.u[1] = cvt2bf(a00.z, a00.w);
        p0.u[2] = cvt2bf(a01.x, a01.y); p0.u[3] = cvt2bf(a01.z, a01.w);
        p1.u[0] = cvt2bf(a10.x, a10.y); p1.u[1] = cvt2bf(a10.z, a10.w);
        p1.u[2] = cvt2bf(a11.x, a11.y); p1.u[3] = cvt2bf(a11.z, a11.w);
        const int k0 = lane * 8;
        *(v8s*)&xlds[g * LDS_PITCH + k0]       = p0.v;   // row g
        *(v8s*)&xlds[(8 + g) * LDS_PITCH + k0] = p1.v;   // row 8+g
        float s0 = (a00.x * a00.x + a00.y * a00.y + a00.z * a00.z + a00.w * a00.w)
                 + (a01.x * a01.x + a01.y * a01.y + a01.z * a01.z + a01.w * a01.w);
        float s1 = (a10.x * a10.x + a10.y * a10.y + a10.z * a10.z + a10.w * a10.w)
                 + (a11.x * a11.x + a11.y * a11.y + a11.z * a11.z + a11.w * a11.w);
#pragma unroll
        for (int off = 32; off >= 1; off >>= 1) {
            s0 += __shfl_xor(s0, off, 64);               // all lanes of wave g
            s1 += __shfl_xor(s1, off, 64);               //   cover row g / 8+g
        }
        if (lane == 0) { xn[g] = s0; xn[8 + g] = s1; }
    }
    __syncthreads();

    // ---- MFMA: wave g computes 16 rows x centroids [16g, 16g+16) ----
    const unsigned short* ap = &xlds[n16 * LDS_PITCH + quad * 8];
    v4f acc0 = (v4f){0.f, 0.f, 0.f, 0.f};
    v4f acc1 = (v4f){0.f, 0.f, 0.f, 0.f};
#pragma unroll
    for (int i = 0; i < 16; i += 2) {                    // 2-way split acc chain
        v8s af0 = *(const v8s*)(ap + i * 32);
        v8s af1 = *(const v8s*)(ap + (i + 1) * 32);
        acc0 = __builtin_amdgcn_mfma_f32_16x16x32_bf16(af0, bfr[i],     acc0, 0, 0, 0);
        acc1 = __builtin_amdgcn_mfma_f32_16x16x32_bf16(af1, bfr[i + 1], acc1, 0, 0, 0);
    }
    v4f acc = acc0 + acc1;

    // ---- epilogue: D layout col=n16, row=quad*4+r ----
    float4 xr = *(const float4*)&xn[quad * 4];
    float xra[4] = {xr.x, xr.y, xr.z, xr.w};
#pragma unroll
    for (int r = 0; r < 4; ++r) {
        int row = rowbase + quad * 4 + r;
        float d2 = xra[r] + cn - 2.0f * acc[r];
        d2 = d2 > 0.f ? d2 : 0.f;
        out[(size_t)row * K_CENT + g * 16 + n16] = sqrtf(d2);
    }
}

extern "C" void kernel_launch(void* const* d_in, const int* in_sizes, int n_in,
                              void* d_out, int out_size, void* d_ws, size_t ws_size,
                              hipStream_t stream) {
    (void)in_sizes; (void)n_in; (void)d_ws; (void)ws_size; (void)out_size;
    const float* x = (const float*)d_in[0];
    const float* c = (const float*)d_in[1];
    float* out = (float*)d_out;
    dist_fused<<<N_ROWS / 16, 512, 0, stream>>>(x, c, out);
}

// Round 3
// 72.009 us; speedup vs baseline: 1.0850x; 1.0850x over previous
//
#include <hip/hip_runtime.h>

#define N_ROWS 8192
#define K_CENT 128
#define D_DIM  512
#define LDS_PITCH 520   // 512 + 8 pad ushorts; row stride 1040B (16B-aligned), dword
                        // stride 260 == 4 (mod 32) -> ds_read_b128 hits the bank floor

typedef short v8s __attribute__((ext_vector_type(8)));
typedef float v4f __attribute__((ext_vector_type(4)));

union U16B { v8s v; unsigned u[4]; };

// HW packed fp32->bf16 (RNE via MODE default): dst = [bf16(lo) | bf16(hi)<<16]
__device__ inline unsigned cvt2bf(float lo, float hi) {
    unsigned r;
    asm("v_cvt_pk_bf16_f32 %0, %1, %2" : "=v"(r) : "v"(lo), "v"(hi));
    return r;
}

// Round-1 structure (measured best: 72.66 us) + full-stream prefetch.
// 256 blocks x 512 threads (8 waves) = exactly 1 block/CU, zero tail.
// Block owns 32 rows as two 16-row LDS tiles (double buffer). c is read ONCE
// per CU (256 KB fp32, L2-resident; 64 MB aggregate = the floor for this
// decomposition -- round 2 proved doubling this costs ~5.5 us). Wave g
// converts its 16 centroids to bf16 once into registers (bfr[16] = 64 VGPR)
// and accumulates exact fp32 ||c||^2 from the same loads.
// CHANGE vs round 1: BOTH tiles' x loads (8x float4 = 32 VGPR) issue before
// the centroid prologue, so the block's entire HBM stream is in flight from
// t=0 and hides under the ~2 us L2-bound c phase, instead of tile 1 starting
// only after the first barrier.
__global__ __launch_bounds__(512, 2) void dist_fused(const float* __restrict__ x,
                                                     const float* __restrict__ c,
                                                     float* __restrict__ out) {
    __shared__ unsigned short xlds[2][16 * LDS_PITCH];
    __shared__ __align__(16) float xn[2][16];

    const int t    = threadIdx.x;
    const int lane = t & 63;
    const int g    = t >> 6;             // wave index == centroid group 0..7
    const int n16  = lane & 15;
    const int quad = lane >> 4;
    const int rowbase = blockIdx.x * 32;

    const float* xs0 = x + (size_t)rowbase * D_DIM;     // tile 0: rows +0..15
    const float* xs1 = xs0 + 16 * D_DIM;                // tile 1: rows +16..31

    // ---- issue ALL x loads up front: full HBM stream in flight at t=0 ----
    // thread t covers floats {t*8 .. t*8+7} of rows g and 8+g of each tile
    float4 a00 = *(const float4*)(xs0 + t * 8);
    float4 a01 = *(const float4*)(xs0 + t * 8 + 4);
    float4 a10 = *(const float4*)(xs0 + 4096 + t * 8);
    float4 a11 = *(const float4*)(xs0 + 4096 + t * 8 + 4);
    float4 b00 = *(const float4*)(xs1 + t * 8);
    float4 b01 = *(const float4*)(xs1 + t * 8 + 4);
    float4 b10 = *(const float4*)(xs1 + 4096 + t * 8);
    float4 b11 = *(const float4*)(xs1 + 4096 + t * 8 + 4);

    // ---- centroid prologue: group g, row n16, quad's k-slices (L2-bound) ----
    const float* cp = c + (size_t)(g * 16 + n16) * D_DIM + quad * 8;
    v8s bfr[16];
    float cn0 = 0.f, cn1 = 0.f, cn2 = 0.f, cn3 = 0.f;
#pragma unroll
    for (int i = 0; i < 16; ++i) {
        float4 u0 = *(const float4*)(cp + i * 32);
        float4 u1 = *(const float4*)(cp + i * 32 + 4);
        U16B b;
        b.u[0] = cvt2bf(u0.x, u0.y); b.u[1] = cvt2bf(u0.z, u0.w);
        b.u[2] = cvt2bf(u1.x, u1.y); b.u[3] = cvt2bf(u1.z, u1.w);
        bfr[i] = b.v;
        cn0 += u0.x * u0.x + u0.y * u0.y;
        cn1 += u0.z * u0.z + u0.w * u0.w;
        cn2 += u1.x * u1.x + u1.y * u1.y;
        cn3 += u1.z * u1.z + u1.w * u1.w;
    }
    float cn = (cn0 + cn1) + (cn2 + cn3);
    cn += __shfl_xor(cn, 16, 64);        // reduce across quad bits (lane bits 4,5)
    cn += __shfl_xor(cn, 32, 64);        // -> exact fp32 ||c[g*16+n16]||^2

    // ---- staging: cvt to LDS + exact fp32 row norms ----
    auto stage = [&](int buf, float4 v00, float4 v01, float4 v10, float4 v11) {
        U16B p0, p1;
        p0.u[0] = cvt2bf(v00.x, v00.y); p0.u[1] = cvt2bf(v00.z, v00.w);
        p0.u[2] = cvt2bf(v01.x, v01.y); p0.u[3] = cvt2bf(v01.z, v01.w);
        p1.u[0] = cvt2bf(v10.x, v10.y); p1.u[1] = cvt2bf(v10.z, v10.w);
        p1.u[2] = cvt2bf(v11.x, v11.y); p1.u[3] = cvt2bf(v11.z, v11.w);
        const int k0 = lane * 8;                           // row g / row 8+g
        *(v8s*)&xlds[buf][g * LDS_PITCH + k0]       = p0.v;
        *(v8s*)&xlds[buf][(8 + g) * LDS_PITCH + k0] = p1.v;
        float s0 = (v00.x * v00.x + v00.y * v00.y + v00.z * v00.z + v00.w * v00.w)
                 + (v01.x * v01.x + v01.y * v01.y + v01.z * v01.z + v01.w * v01.w);
        float s1 = (v10.x * v10.x + v10.y * v10.y + v10.z * v10.z + v10.w * v10.w)
                 + (v11.x * v11.x + v11.y * v11.y + v11.z * v11.z + v11.w * v11.w);
#pragma unroll
        for (int off = 32; off >= 1; off >>= 1) {
            s0 += __shfl_xor(s0, off, 64);
            s1 += __shfl_xor(s1, off, 64);
        }
        if (lane == 0) { xn[buf][g] = s0; xn[buf][8 + g] = s1; }
    };

    // ---- MFMA + epilogue for one tile ----
    auto compute = [&](int buf, int tilebase) {
        const unsigned short* ap = &xlds[buf][n16 * LDS_PITCH + quad * 8];
        v4f acc0 = (v4f){0.f, 0.f, 0.f, 0.f};
        v4f acc1 = (v4f){0.f, 0.f, 0.f, 0.f};
#pragma unroll
        for (int i = 0; i < 16; i += 2) {                  // 2-way split acc chain
            v8s af0 = *(const v8s*)(ap + i * 32);
            v8s af1 = *(const v8s*)(ap + (i + 1) * 32);
            acc0 = __builtin_amdgcn_mfma_f32_16x16x32_bf16(af0, bfr[i],     acc0, 0, 0, 0);
            acc1 = __builtin_amdgcn_mfma_f32_16x16x32_bf16(af1, bfr[i + 1], acc1, 0, 0, 0);
        }
        v4f acc = acc0 + acc1;
        float4 xr = *(const float4*)&xn[buf][quad * 4];    // rows quad*4 + 0..3
        float xra[4] = {xr.x, xr.y, xr.z, xr.w};
#pragma unroll
        for (int r = 0; r < 4; ++r) {
            int row = tilebase + quad * 4 + r;             // D layout: col=n16, row=quad*4+r
            float d2 = xra[r] + cn - 2.0f * acc[r];
            d2 = d2 > 0.f ? d2 : 0.f;
            out[(size_t)row * K_CENT + g * 16 + n16] = sqrtf(d2);
        }
    };

    stage(0, a00, a01, a10, a11);
    __syncthreads();
    compute(0, rowbase);
    stage(1, b00, b01, b10, b11);
    __syncthreads();
    compute(1, rowbase + 16);
}

extern "C" void kernel_launch(void* const* d_in, const int* in_sizes, int n_in,
                              void* d_out, int out_size, void* d_ws, size_t ws_size,
                              hipStream_t stream) {
    (void)in_sizes; (void)n_in; (void)d_ws; (void)ws_size; (void)out_size;
    const float* x = (const float*)d_in[0];
    const float* c = (const float*)d_in[1];
    float* out = (float*)d_out;
    dist_fused<<<N_ROWS / 32, 512, 0, stream>>>(x, c, out);
}